// Round 3
// baseline (143.038 us; speedup 1.0000x reference)
//
#include <hip/hip_runtime.h>
#include <hip/hip_bf16.h>

typedef float f32x4 __attribute__((ext_vector_type(4)));
typedef short s16x8 __attribute__((ext_vector_type(8)));
typedef __bf16 bf16x8 __attribute__((ext_vector_type(8)));
typedef unsigned short u16;

#define NSEQ 1024
#define EDIM 256

// ---- bf16 round-to-nearest-even cast ----
__device__ __forceinline__ u16 f2bf(float f){
  union { float f; unsigned u; } v; v.f = f;
  unsigned r = v.u + 0x7FFF + ((v.u >> 16) & 1);
  return (u16)(r >> 16);
}
__device__ __forceinline__ float bf2f(u16 b){
  union { float f; unsigned u; } v; v.u = ((unsigned)b) << 16;
  return v.f;
}

// ---- MFMA wrapper with SFINAE hedge on builtin operand type (v8i16 vs v8bf16) ----
template <typename V>
__device__ __forceinline__ auto mfma_impl(V a, V b, f32x4 c, int)
    -> decltype(__builtin_amdgcn_mfma_f32_16x16x32_bf16(a, b, c, 0, 0, 0)) {
  return __builtin_amdgcn_mfma_f32_16x16x32_bf16(a, b, c, 0, 0, 0);
}
template <typename V>
__device__ __forceinline__ f32x4 mfma_impl(V a, V b, f32x4 c, long){
  bf16x8 ab = __builtin_bit_cast(bf16x8, a);
  bf16x8 bb = __builtin_bit_cast(bf16x8, b);
  return __builtin_amdgcn_mfma_f32_16x16x32_bf16(ab, bb, c, 0, 0, 0);
}
__device__ __forceinline__ f32x4 mfma16(s16x8 a, s16x8 b, f32x4 c){
  return mfma_impl(a, b, c, 0);
}

__device__ __forceinline__ void gload_lds16(const u16* g, u16* l){
  __builtin_amdgcn_global_load_lds((const __attribute__((address_space(1))) void*)g,
                                   (__attribute__((address_space(3))) void*)l, 16, 0, 0);
}

// ---- K0: cast W_v, W_o to bf16 fragment layout; extract w_q column ----
// frag layout per W: [c 8][ks 8][nt 2][lane 64][j 8], element = W[ks*32+8*(l>>4)+j][c*32+nt*16+(l&15)]
__global__ void k0_prep(const float* __restrict__ Wqkv, const float* __restrict__ Wo,
                        u16* __restrict__ wvf, u16* __restrict__ wof, float* __restrict__ wqc){
  int t = blockIdx.x * 256 + threadIdx.x;
  if (t < 16384){
    int which = t >> 13;
    int slot  = t & 8191;
    int l  = slot & 63;
    int nt = (slot >> 6) & 1;
    int ks = (slot >> 7) & 7;
    int c  = (slot >> 10) & 7;
    int row = ks*32 + 8*(l>>4);
    int col = c*32 + nt*16 + (l&15);
    s16x8 o8;
    if (which == 0){
      for (int j=0;j<8;j++) o8[j] = (short)f2bf(Wqkv[(size_t)(row+j)*513 + 257 + col]);
      *(s16x8*)(wvf + (size_t)slot*8) = o8;
    } else {
      for (int j=0;j<8;j++) o8[j] = (short)f2bf(Wo[(size_t)(row+j)*256 + col]);
      *(s16x8*)(wof + (size_t)slot*8) = o8;
    }
  } else if (t < 16384 + 256){
    int d = t - 16384;
    wqc[d] = Wqkv[(size_t)d*513];    // W_qkv[:,0] contiguous copy
  }
}

// ---- K1: per 16-row tile: q = x.wq + b0 ; x -> bf16 A-frag layout ----
// x_frag: [bp 128][rt16 64][ks 8][lane 64][j 8], elem = x[rt16*16+(l&15)][ks*32+8*(l>>4)+j]
__global__ void k1_qfrag(const float* __restrict__ x, const float* __restrict__ wqc,
                         const float* __restrict__ bqkv, u16* __restrict__ xf, float* __restrict__ q){
  int bp = blockIdx.x >> 6, rt = blockIdx.x & 63;
  const float* xt = x + ((size_t)bp*NSEQ + rt*16) * EDIM;
  __shared__ float xl[16][260];     // +4 pad: breaks bank aliasing on strided row reads
  int tid = threadIdx.x;
  for (int i=0;i<4;i++){
    int idx = tid + i*256;
    float4 vv = ((const float4*)xt)[idx];
    int row = idx >> 6, c4 = idx & 63;
    *(float4*)&xl[row][c4*4] = vv;
  }
  __syncthreads();
  int l = tid & 63, w = tid >> 6;
  int lo = l & 15, hi = l >> 4;
  for (int kk=0;kk<2;kk++){
    int ks = w*2 + kk;
    int k0 = ks*32 + 8*hi;
    s16x8 o8;
    for (int j=0;j<8;j++) o8[j] = (short)f2bf(xl[lo][k0+j]);
    size_t fo = ((((size_t)bp*64 + rt)*8 + ks)*64 + l) * 8;
    *(s16x8*)(xf + fo) = o8;
  }
  // q rows: wave w handles rows 4w..4w+3, 64-lane dot over 256 cols
  int c = l*4;
  float4 wv4 = *(const float4*)(wqc + c);
  float b0 = bqkv[0];
  for (int r=0;r<4;r++){
    int row = w*4 + r;
    float4 xv = *(float4*)&xl[row][c];
    float p = xv.x*wv4.x + xv.y*wv4.y + xv.z*wv4.z + xv.w*wv4.w;
    for (int o=32;o;o>>=1) p += __shfl_down(p, o);
    if (l == 0) q[(size_t)bp*NSEQ + rt*16 + row] = p + b0;
  }
}

// ---- K2: softmax over N=1024 per (b,p) ----
__global__ void k2_softmax(const float* __restrict__ q, float* __restrict__ s){
  int bp = blockIdx.x, tid = threadIdx.x;
  float4 v = ((const float4*)(q + (size_t)bp*NSEQ))[tid];
  __shared__ float red[8];
  float m = fmaxf(fmaxf(v.x, v.y), fmaxf(v.z, v.w));
  for (int o=32;o;o>>=1) m = fmaxf(m, __shfl_xor(m, o));
  if ((tid & 63) == 0) red[tid >> 6] = m;
  __syncthreads();
  m = fmaxf(fmaxf(red[0], red[1]), fmaxf(red[2], red[3]));
  float e0 = expf(v.x - m), e1 = expf(v.y - m), e2 = expf(v.z - m), e3 = expf(v.w - m);
  float sum = e0 + e1 + e2 + e3;
  for (int o=32;o;o>>=1) sum += __shfl_xor(sum, o);
  if ((tid & 63) == 0) red[4 + (tid >> 6)] = sum;
  __syncthreads();
  float inv = 1.0f / (red[4] + red[5] + red[6] + red[7]);
  float4 o4 = {e0*inv, e1*inv, e2*inv, e3*inv};
  ((float4*)(s + (size_t)bp*NSEQ))[tid] = o4;
}

// ---- K3: t[bp][d] = sum_n s[n]*x[n][d], reading bf16 x-frags (half the bytes of fp32 x) ----
// grid: (bp, ks) = 128 x 8; block covers all 1024 n for 32 d-columns.
__global__ void k3_tpart(const u16* __restrict__ xf, const float* __restrict__ s, float* __restrict__ tp){
  int bp = blockIdx.x >> 3, ks = blockIdx.x & 7;
  int tid = threadIdx.x, l = tid & 63, w = tid >> 6;
  int lo = l & 15, hi = l >> 4;
  const float* sb = s + (size_t)bp*NSEQ;
  float acc[8];
  for (int j=0;j<8;j++) acc[j] = 0.f;
  for (int rti=0; rti<16; rti++){
    int rt = w*16 + rti;
    s16x8 v = *(const s16x8*)(xf + ((((size_t)bp*64 + rt)*8 + ks)*64 + l)*8);
    float sv = sb[rt*16 + lo];
    for (int j=0;j<8;j++) acc[j] += sv * bf2f((u16)v[j]);
  }
  // reduce over lo (lane bits 0..3): all x-rows handled by this wave
  for (int j=0;j<8;j++)
    for (int m=1;m<16;m<<=1) acc[j] += __shfl_xor(acc[j], m);
  __shared__ float red[4][32];
  if (lo == 0)
    for (int j=0;j<8;j++) red[w][8*hi + j] = acc[j];
  __syncthreads();
  if (tid < 32){
    float t = red[0][tid] + red[1][tid] + red[2][tid] + red[3][tid];
    tp[(size_t)bp*EDIM + ks*32 + tid] = t;
  }
}

// ---- K4: cv[bp][e] = b_k[e] + sum_d t[d]*W_k[d][e] ----
__global__ void k4_cv(const float* __restrict__ tp, const float* __restrict__ Wqkv,
                      const float* __restrict__ bqkv, float* __restrict__ cv){
  int bp = blockIdx.x, e = threadIdx.x;
  __shared__ float tl[256];
  tl[e] = tp[(size_t)bp*EDIM + e];
  __syncthreads();
  float acc = bqkv[1 + e];
  for (int d=0;d<256;d++) acc += tl[d] * Wqkv[(size_t)d*513 + 1 + e];
  cv[(size_t)bp*EDIM + e] = acc;
}

// ---- K5: out = (relu(x@Wv + bv) * cv) @ Wo + bo ----
// 4 waves x 32 rows (2 rowsets of 16) = 128 rows/block; 1024 blocks.
// Double-buffered W chunks; h -> GEMM2 A-frags via tiny wave-private LDS transpose slice.
__global__ __launch_bounds__(256) void k5_main(
    const u16* __restrict__ xf, const u16* __restrict__ wvf, const u16* __restrict__ wof,
    const float* __restrict__ bqkv, const float* __restrict__ bo,
    const float* __restrict__ cv, float* __restrict__ out){
  int bp = blockIdx.x >> 3, rt = blockIdx.x & 7;
  int tid = threadIdx.x, l = tid & 63, w = tid >> 6;
  int lo = l & 15, hi = l >> 4;
  __shared__ u16 WBUF[2][16][512];   // double-buffered 16 KB W chunk (32 cols, full K)
  __shared__ u16 HB[4][16][40];      // per-wave h transpose slice: 16 x 32 (+8 pad)

  // A-frags for 2 rowsets (16-row tiles 2w, 2w+1 of this 128-row block)
  s16x8 af[2][8];
#pragma unroll
  for (int s=0;s<2;s++){
    const u16* src = xf + ((((size_t)bp*64 + rt*8 + 2*w + s)*8)*64 + l)*8;
#pragma unroll
    for (int ks=0;ks<8;ks++) af[s][ks] = *(const s16x8*)(src + (size_t)ks*512);
  }
  const float* cvb = cv + (size_t)bp*EDIM;

  // prologue: stage Wv chunk 0 into WBUF[0]
  {
    const u16* gsrc = wvf + (size_t)(w*4)*512 + l*8;
#pragma unroll
    for (int i=0;i<4;i++) gload_lds16(gsrc + i*512, &WBUF[0][w*4 + i][0]);
  }
  __syncthreads();   // drains vmcnt(0): chunk 0 staged

  s16x8 hf[2][8];

  // Phase A: h = relu(x@Wv + bv) * cv, chunk c = output cols c*32..+31 = GEMM2 K-chunk c
#pragma unroll
  for (int c=0;c<8;c++){
    int cur = c & 1;
    // prefetch next chunk (c==7 prefetches Wo chunk 0) into the other buffer
    {
      const u16* nsrc = (c < 7) ? (wvf + (size_t)(c+1)*8192) : wof;
      const u16* gsrc = nsrc + (size_t)(w*4)*512 + l*8;
#pragma unroll
      for (int i=0;i<4;i++) gload_lds16(gsrc + i*512, &WBUF[cur^1][w*4 + i][0]);
    }
#pragma unroll
    for (int s=0;s<2;s++){
#pragma unroll
      for (int nt=0;nt<2;nt++){
        f32x4 acc = {0.f,0.f,0.f,0.f};
#pragma unroll
        for (int ks=0;ks<8;ks++){
          s16x8 b = *(const s16x8*)&WBUF[cur][ks*2 + nt][l*8];
          acc = mfma16(af[s][ks], b, acc);
        }
        int col = c*32 + nt*16 + lo;
        float bv = bqkv[257 + col], cs = cvb[col];
#pragma unroll
        for (int r=0;r<4;r++){
          float h = acc[r] + bv;
          h = h > 0.f ? h : 0.f;
          HB[w][hi*4 + r][nt*16 + lo] = f2bf(h * cs);   // C-layout scatter, wave-private
        }
      }
      // re-read as GEMM2 A-frag (wave-local; lgkmcnt dependency handled by compiler)
      hf[s][c] = *(const s16x8*)&HB[w][lo][8*hi];
    }
    __syncthreads();   // prefetched W visible; all waves done reading WBUF[cur]
  }

  // Phase B: out = h @ Wo + bo (buffers keep alternating; chunk c2 uses buffer c2&1)
#pragma unroll
  for (int c2=0;c2<8;c2++){
    int cur = c2 & 1;
    if (c2 < 7){
      const u16* gsrc = wof + (size_t)(c2+1)*8192 + (size_t)(w*4)*512 + l*8;
#pragma unroll
      for (int i=0;i<4;i++) gload_lds16(gsrc + i*512, &WBUF[cur^1][w*4 + i][0]);
    }
#pragma unroll
    for (int s=0;s<2;s++){
      float* ob = out + ((size_t)bp*NSEQ + (rt*8 + 2*w + s)*16) * EDIM;
#pragma unroll
      for (int nt=0;nt<2;nt++){
        f32x4 acc = {0.f,0.f,0.f,0.f};
#pragma unroll
        for (int ks=0;ks<8;ks++){
          s16x8 b = *(const s16x8*)&WBUF[cur][ks*2 + nt][l*8];
          acc = mfma16(hf[s][ks], b, acc);
        }
        int col = c2*32 + nt*16 + lo;
        float bb = bo[col];
#pragma unroll
        for (int r=0;r<4;r++)
          ob[(size_t)(hi*4 + r)*EDIM + col] = acc[r] + bb;
      }
    }
    if (c2 < 7) __syncthreads();
  }
}

extern "C" void kernel_launch(void* const* d_in, const int* in_sizes, int n_in,
                              void* d_out, int out_size, void* d_ws, size_t ws_size,
                              hipStream_t stream){
  const float* x    = (const float*)d_in[0];
  const float* Wqkv = (const float*)d_in[1];
  const float* bqkv = (const float*)d_in[2];
  const float* Wo   = (const float*)d_in[3];
  const float* bo   = (const float*)d_in[4];
  float* out = (float*)d_out;
  char* ws = (char*)d_ws;
  // workspace layout (all 16B-aligned)
  u16*   xf  = (u16*)(ws);                       // 67108864 B
  u16*   wvf = (u16*)(ws + 67108864);            //   131072 B
  u16*   wof = (u16*)(ws + 67239936);            //   131072 B
  float* q   = (float*)(ws + 67371008);          //   524288 B
  float* s   = (float*)(ws + 67895296);          //   524288 B
  float* tp  = (float*)(ws + 68419584);          //   131072 B (t, final)
  float* cvv = (float*)(ws + 69468160);          //   131072 B
  float* wqc = (float*)(ws + 69599232);          //     1024 B

  hipLaunchKernelGGL(k0_prep,    dim3(65),   dim3(256), 0, stream, Wqkv, Wo, wvf, wof, wqc);
  hipLaunchKernelGGL(k1_qfrag,   dim3(8192), dim3(256), 0, stream, x, wqc, bqkv, xf, q);
  hipLaunchKernelGGL(k2_softmax, dim3(128),  dim3(256), 0, stream, q, s);
  hipLaunchKernelGGL(k3_tpart,   dim3(1024), dim3(256), 0, stream, xf, s, tp);
  hipLaunchKernelGGL(k4_cv,      dim3(128),  dim3(256), 0, stream, tp, Wqkv, bqkv, cvv);
  hipLaunchKernelGGL(k5_main,    dim3(1024), dim3(256), 0, stream, xf, wvf, wof, bqkv, bo, cvv, out);
}

// Round 4
// 130.114 us; speedup vs baseline: 1.0993x; 1.0993x over previous
//
#include <hip/hip_runtime.h>
#include <hip/hip_bf16.h>

typedef float f32x4 __attribute__((ext_vector_type(4)));
typedef short s16x8 __attribute__((ext_vector_type(8)));
typedef __bf16 bf16x8 __attribute__((ext_vector_type(8)));
typedef unsigned short u16;

#define NSEQ 1024
#define EDIM 256

#define WAITVM(N) asm volatile("s_waitcnt vmcnt(" #N ")" ::: "memory")

// ---- bf16 round-to-nearest-even cast ----
__device__ __forceinline__ u16 f2bf(float f){
  union { float f; unsigned u; } v; v.f = f;
  unsigned r = v.u + 0x7FFF + ((v.u >> 16) & 1);
  return (u16)(r >> 16);
}
__device__ __forceinline__ float bf2f(u16 b){
  union { float f; unsigned u; } v; v.u = ((unsigned)b) << 16;
  return v.f;
}

// ---- MFMA wrapper with SFINAE hedge on builtin operand type (v8i16 vs v8bf16) ----
template <typename V>
__device__ __forceinline__ auto mfma_impl(V a, V b, f32x4 c, int)
    -> decltype(__builtin_amdgcn_mfma_f32_16x16x32_bf16(a, b, c, 0, 0, 0)) {
  return __builtin_amdgcn_mfma_f32_16x16x32_bf16(a, b, c, 0, 0, 0);
}
template <typename V>
__device__ __forceinline__ f32x4 mfma_impl(V a, V b, f32x4 c, long){
  bf16x8 ab = __builtin_bit_cast(bf16x8, a);
  bf16x8 bb = __builtin_bit_cast(bf16x8, b);
  return __builtin_amdgcn_mfma_f32_16x16x32_bf16(ab, bb, c, 0, 0, 0);
}
__device__ __forceinline__ f32x4 mfma16(s16x8 a, s16x8 b, f32x4 c){
  return mfma_impl(a, b, c, 0);
}

__device__ __forceinline__ void gload_lds16(const u16* g, u16* l){
  __builtin_amdgcn_global_load_lds((const __attribute__((address_space(1))) void*)g,
                                   (__attribute__((address_space(3))) void*)l, 16, 0, 0);
}

// ---- K0: cast W_v, W_o to bf16 fragment layout; extract w_q column ----
// frag layout per W: [c 8][ks 8][nt 2][lane 64][j 8], element = W[ks*32+8*(l>>4)+j][c*32+nt*16+(l&15)]
__global__ void k0_prep(const float* __restrict__ Wqkv, const float* __restrict__ Wo,
                        u16* __restrict__ wvf, u16* __restrict__ wof, float* __restrict__ wqc){
  int t = blockIdx.x * 256 + threadIdx.x;
  if (t < 16384){
    int which = t >> 13;
    int slot  = t & 8191;
    int l  = slot & 63;
    int nt = (slot >> 6) & 1;
    int ks = (slot >> 7) & 7;
    int c  = (slot >> 10) & 7;
    int row = ks*32 + 8*(l>>4);
    int col = c*32 + nt*16 + (l&15);
    s16x8 o8;
    if (which == 0){
      for (int j=0;j<8;j++) o8[j] = (short)f2bf(Wqkv[(size_t)(row+j)*513 + 257 + col]);
      *(s16x8*)(wvf + (size_t)slot*8) = o8;
    } else {
      for (int j=0;j<8;j++) o8[j] = (short)f2bf(Wo[(size_t)(row+j)*256 + col]);
      *(s16x8*)(wof + (size_t)slot*8) = o8;
    }
  } else if (t < 16384 + 256){
    int d = t - 16384;
    wqc[d] = Wqkv[(size_t)d*513];    // W_qkv[:,0] contiguous copy
  }
}

// ---- K1: per 16-row tile: q = x.wq + b0 ; x -> bf16 A-frag layout ----
// x_frag: [bp 128][rt16 64][ks 8][lane 64][j 8], elem = x[rt16*16+(l&15)][ks*32+8*(l>>4)+j]
__global__ void k1_qfrag(const float* __restrict__ x, const float* __restrict__ wqc,
                         const float* __restrict__ bqkv, u16* __restrict__ xf, float* __restrict__ q){
  int bp = blockIdx.x >> 6, rt = blockIdx.x & 63;
  const float* xt = x + ((size_t)bp*NSEQ + rt*16) * EDIM;
  __shared__ float xl[16][260];     // +4 pad: breaks bank aliasing on strided row reads
  int tid = threadIdx.x;
  for (int i=0;i<4;i++){
    int idx = tid + i*256;
    float4 vv = ((const float4*)xt)[idx];
    int row = idx >> 6, c4 = idx & 63;
    *(float4*)&xl[row][c4*4] = vv;
  }
  __syncthreads();
  int l = tid & 63, w = tid >> 6;
  int lo = l & 15, hi = l >> 4;
  for (int kk=0;kk<2;kk++){
    int ks = w*2 + kk;
    int k0 = ks*32 + 8*hi;
    s16x8 o8;
    for (int j=0;j<8;j++) o8[j] = (short)f2bf(xl[lo][k0+j]);
    size_t fo = ((((size_t)bp*64 + rt)*8 + ks)*64 + l) * 8;
    *(s16x8*)(xf + fo) = o8;
  }
  // q rows: wave w handles rows 4w..4w+3, 64-lane dot over 256 cols
  int c = l*4;
  float4 wv4 = *(const float4*)(wqc + c);
  float b0 = bqkv[0];
  for (int r=0;r<4;r++){
    int row = w*4 + r;
    float4 xv = *(float4*)&xl[row][c];
    float p = xv.x*wv4.x + xv.y*wv4.y + xv.z*wv4.z + xv.w*wv4.w;
    for (int o=32;o;o>>=1) p += __shfl_down(p, o);
    if (l == 0) q[(size_t)bp*NSEQ + rt*16 + row] = p + b0;
  }
}

// ---- K2: softmax over N=1024 per (b,p) ----
__global__ void k2_softmax(const float* __restrict__ q, float* __restrict__ s){
  int bp = blockIdx.x, tid = threadIdx.x;
  float4 v = ((const float4*)(q + (size_t)bp*NSEQ))[tid];
  __shared__ float red[8];
  float m = fmaxf(fmaxf(v.x, v.y), fmaxf(v.z, v.w));
  for (int o=32;o;o>>=1) m = fmaxf(m, __shfl_xor(m, o));
  if ((tid & 63) == 0) red[tid >> 6] = m;
  __syncthreads();
  m = fmaxf(fmaxf(red[0], red[1]), fmaxf(red[2], red[3]));
  float e0 = expf(v.x - m), e1 = expf(v.y - m), e2 = expf(v.z - m), e3 = expf(v.w - m);
  float sum = e0 + e1 + e2 + e3;
  for (int o=32;o;o>>=1) sum += __shfl_xor(sum, o);
  if ((tid & 63) == 0) red[4 + (tid >> 6)] = sum;
  __syncthreads();
  float inv = 1.0f / (red[4] + red[5] + red[6] + red[7]);
  float4 o4 = {e0*inv, e1*inv, e2*inv, e3*inv};
  ((float4*)(s + (size_t)bp*NSEQ))[tid] = o4;
}

// ---- K3: t[bp][d] = sum_n s[n]*x[n][d], reading bf16 x-frags ----
__global__ void k3_tpart(const u16* __restrict__ xf, const float* __restrict__ s, float* __restrict__ tp){
  int bp = blockIdx.x >> 3, ks = blockIdx.x & 7;
  int tid = threadIdx.x, l = tid & 63, w = tid >> 6;
  int lo = l & 15, hi = l >> 4;
  const float* sb = s + (size_t)bp*NSEQ;
  float acc[8];
  for (int j=0;j<8;j++) acc[j] = 0.f;
  for (int rti=0; rti<16; rti++){
    int rt = w*16 + rti;
    s16x8 v = *(const s16x8*)(xf + ((((size_t)bp*64 + rt)*8 + ks)*64 + l)*8);
    float sv = sb[rt*16 + lo];
    for (int j=0;j<8;j++) acc[j] += sv * bf2f((u16)v[j]);
  }
  for (int j=0;j<8;j++)
    for (int m=1;m<16;m<<=1) acc[j] += __shfl_xor(acc[j], m);
  __shared__ float red[4][32];
  if (lo == 0)
    for (int j=0;j<8;j++) red[w][8*hi + j] = acc[j];
  __syncthreads();
  if (tid < 32){
    float t = red[0][tid] + red[1][tid] + red[2][tid] + red[3][tid];
    tp[(size_t)bp*EDIM + ks*32 + tid] = t;
  }
}

// ---- K4: cv[bp][e] = b_k[e] + sum_d t[d]*W_k[d][e] ----
__global__ void k4_cv(const float* __restrict__ tp, const float* __restrict__ Wqkv,
                      const float* __restrict__ bqkv, float* __restrict__ cv){
  int bp = blockIdx.x, e = threadIdx.x;
  __shared__ float tl[256];
  tl[e] = tp[(size_t)bp*EDIM + e];
  __syncthreads();
  float acc = bqkv[1 + e];
  for (int d=0;d<256;d++) acc += tl[d] * Wqkv[(size_t)d*513 + 1 + e];
  cv[(size_t)bp*EDIM + e] = acc;
}

// ---- K5: out = (relu(x@Wv + bv) * cv) @ Wo + bo ----
// 4 waves x 32 rows (2 rowsets) = 128 rows/block; 1024 blocks.
// Fused 16-chunk loop (8 Wv then 8 Wo), 3-buffer LDS ring, prefetch depth 2,
// raw s_barrier + counted vmcnt (stores never drained). launch_bounds(256,2)
// keeps af/hf fragment arrays (128 VGPRs) register-resident.
__global__ __launch_bounds__(256, 2) void k5_main(
    const u16* __restrict__ xf, const u16* __restrict__ wvf, const u16* __restrict__ wof,
    const float* __restrict__ bqkv, const float* __restrict__ bo,
    const float* __restrict__ cv, float* __restrict__ out){
  int bp = blockIdx.x >> 3, rt = blockIdx.x & 7;
  int tid = threadIdx.x, l = tid & 63, w = tid >> 6;
  int lo = l & 15, hi = l >> 4;
  __shared__ u16 WBUF[3][16][512];   // 3-buffer ring of 16 KB W chunks (32 cols, full K)
  __shared__ u16 HB[4][2][16][40];   // per-wave, per-rowset h transpose slices

  // A-frags for 2 rowsets (16-row tiles 2w, 2w+1 of this 128-row block)
  s16x8 af0[8], af1[8];
  {
    const u16* src0 = xf + ((((size_t)bp*64 + rt*8 + 2*w + 0)*8)*64 + l)*8;
    const u16* src1 = src0 + 4096;
#pragma unroll
    for (int ks=0;ks<8;ks++){
      af0[ks] = *(const s16x8*)(src0 + (size_t)ks*512);
      af1[ks] = *(const s16x8*)(src1 + (size_t)ks*512);
    }
  }
  const float* cvb = cv + (size_t)bp*EDIM;
  float* ob0 = out + ((size_t)bp*NSEQ + (rt*8 + 2*w + 0)*16) * EDIM;
  float* ob1 = ob0 + 16*EDIM;

  // stage W chunk (0..7 = Wv, 8..15 = Wo) into ring buffer
  auto stage = [&](int chunk, int buf){
    const u16* base = (chunk < 8) ? (wvf + (size_t)chunk*8192) : (wof + (size_t)(chunk-8)*8192);
    const u16* gsrc = base + (size_t)(w*4)*512 + l*8;
#pragma unroll
    for (int i=0;i<4;i++) gload_lds16(gsrc + i*512, &WBUF[buf][w*4 + i][0]);
  };

  // prologue: stage chunks 0,1
  stage(0, 0);
  stage(1, 1);
  WAITVM(4);                       // chunk 0 staged (chunk 1's 4 loads may remain)
  __builtin_amdgcn_s_barrier();
  __builtin_amdgcn_sched_barrier(0);

  s16x8 hf0[8], hf1[8];

#pragma unroll
  for (int c=0;c<16;c++){
    const int buf = c % 3;
    f32x4 acc00 = {0.f,0.f,0.f,0.f}, acc01 = acc00, acc10 = acc00, acc11 = acc00;
    auto do_mfma = [&](const s16x8 (&A0)[8], const s16x8 (&A1)[8]){
#pragma unroll
      for (int ks=0;ks<8;ks++){
        s16x8 b0 = *(const s16x8*)&WBUF[buf][ks*2 + 0][l*8];
        s16x8 b1 = *(const s16x8*)&WBUF[buf][ks*2 + 1][l*8];
        acc00 = mfma16(A0[ks], b0, acc00);
        acc10 = mfma16(A1[ks], b0, acc10);
        acc01 = mfma16(A0[ks], b1, acc01);
        acc11 = mfma16(A1[ks], b1, acc11);
      }
    };
    if (c < 8) do_mfma(af0, af1); else do_mfma(hf0, hf1);

    if (c < 8){
      // epilogue A: h = relu(acc+bv)*cv -> HB scatter -> hf A-frags (wave-private LDS)
      int colA = c*32 + lo, colB = colA + 16;
      float bvA = bqkv[257 + colA], bvB = bqkv[257 + colB];
      float csA = cvb[colA],        csB = cvb[colB];
#pragma unroll
      for (int r=0;r<4;r++){
        float h00 = acc00[r] + bvA, h01 = acc01[r] + bvB;
        float h10 = acc10[r] + bvA, h11 = acc11[r] + bvB;
        HB[w][0][hi*4 + r][lo]      = f2bf(h00 > 0.f ? h00*csA : 0.f);
        HB[w][0][hi*4 + r][16 + lo] = f2bf(h01 > 0.f ? h01*csB : 0.f);
        HB[w][1][hi*4 + r][lo]      = f2bf(h10 > 0.f ? h10*csA : 0.f);
        HB[w][1][hi*4 + r][16 + lo] = f2bf(h11 > 0.f ? h11*csB : 0.f);
      }
      hf0[c] = *(const s16x8*)&HB[w][0][lo][8*hi];
      hf1[c] = *(const s16x8*)&HB[w][1][lo][8*hi];
    } else {
      // epilogue B: out stores (never drained by the counted waits below)
      int c2 = c - 8;
      int colA = c2*32 + lo, colB = colA + 16;
      float bbA = bo[colA], bbB = bo[colB];
#pragma unroll
      for (int r=0;r<4;r++){
        ob0[(size_t)(hi*4 + r)*EDIM + colA] = acc00[r] + bbA;
        ob0[(size_t)(hi*4 + r)*EDIM + colB] = acc01[r] + bbB;
        ob1[(size_t)(hi*4 + r)*EDIM + colA] = acc10[r] + bbA;
        ob1[(size_t)(hi*4 + r)*EDIM + colB] = acc11[r] + bbB;
      }
    }

    // stage chunk c+2 into the buffer freed at end of iter c-1
    if (c + 2 <= 15) stage(c + 2, (c + 2) % 3);

    // counted waits: ensure chunk c+1 staged; never drain this iter's stores.
    // A iters: younger ops = stage(c+2) only -> vmcnt(4).
    // B steady: younger = 16 stores + stage(c+2) -> vmcnt(20).
    // c=14: no stage -> younger = 16 stores -> vmcnt(16). c=15: done.
    if (c < 8)       WAITVM(4);
    else if (c < 14) WAITVM(20);
    else if (c == 14) WAITVM(16);
    if (c < 15){
      __builtin_amdgcn_s_barrier();
      __builtin_amdgcn_sched_barrier(0);
    }
  }
}

extern "C" void kernel_launch(void* const* d_in, const int* in_sizes, int n_in,
                              void* d_out, int out_size, void* d_ws, size_t ws_size,
                              hipStream_t stream){
  const float* x    = (const float*)d_in[0];
  const float* Wqkv = (const float*)d_in[1];
  const float* bqkv = (const float*)d_in[2];
  const float* Wo   = (const float*)d_in[3];
  const float* bo   = (const float*)d_in[4];
  float* out = (float*)d_out;
  char* ws = (char*)d_ws;
  u16*   xf  = (u16*)(ws);                       // 67108864 B
  u16*   wvf = (u16*)(ws + 67108864);            //   131072 B
  u16*   wof = (u16*)(ws + 67239936);            //   131072 B
  float* q   = (float*)(ws + 67371008);          //   524288 B
  float* s   = (float*)(ws + 67895296);          //   524288 B
  float* tp  = (float*)(ws + 68419584);          //   131072 B
  float* cvv = (float*)(ws + 69468160);          //   131072 B
  float* wqc = (float*)(ws + 69599232);          //     1024 B

  hipLaunchKernelGGL(k0_prep,    dim3(65),   dim3(256), 0, stream, Wqkv, Wo, wvf, wof, wqc);
  hipLaunchKernelGGL(k1_qfrag,   dim3(8192), dim3(256), 0, stream, x, wqc, bqkv, xf, q);
  hipLaunchKernelGGL(k2_softmax, dim3(128),  dim3(256), 0, stream, q, s);
  hipLaunchKernelGGL(k3_tpart,   dim3(1024), dim3(256), 0, stream, xf, s, tp);
  hipLaunchKernelGGL(k4_cv,      dim3(128),  dim3(256), 0, stream, tp, Wqkv, bqkv, cvv);
  hipLaunchKernelGGL(k5_main,    dim3(1024), dim3(256), 0, stream, xf, wvf, wof, bqkv, bo, cvv, out);
}

// Round 5
// 124.632 us; speedup vs baseline: 1.1477x; 1.0440x over previous
//
#include <hip/hip_runtime.h>
#include <hip/hip_bf16.h>

typedef float f32x4 __attribute__((ext_vector_type(4)));
typedef short s16x8 __attribute__((ext_vector_type(8)));
typedef __bf16 bf16x8 __attribute__((ext_vector_type(8)));
typedef unsigned short u16;

#define NSEQ 1024
#define EDIM 256

#define WAITVM(N) asm volatile("s_waitcnt vmcnt(" #N ")" ::: "memory")

// ---- bf16 round-to-nearest-even cast ----
__device__ __forceinline__ u16 f2bf(float f){
  union { float f; unsigned u; } v; v.f = f;
  unsigned r = v.u + 0x7FFF + ((v.u >> 16) & 1);
  return (u16)(r >> 16);
}
__device__ __forceinline__ float bf2f(u16 b){
  union { float f; unsigned u; } v; v.u = ((unsigned)b) << 16;
  return v.f;
}

// ---- MFMA wrapper with SFINAE hedge on builtin operand type (v8i16 vs v8bf16) ----
template <typename V>
__device__ __forceinline__ auto mfma_impl(V a, V b, f32x4 c, int)
    -> decltype(__builtin_amdgcn_mfma_f32_16x16x32_bf16(a, b, c, 0, 0, 0)) {
  return __builtin_amdgcn_mfma_f32_16x16x32_bf16(a, b, c, 0, 0, 0);
}
template <typename V>
__device__ __forceinline__ f32x4 mfma_impl(V a, V b, f32x4 c, long){
  bf16x8 ab = __builtin_bit_cast(bf16x8, a);
  bf16x8 bb = __builtin_bit_cast(bf16x8, b);
  return __builtin_amdgcn_mfma_f32_16x16x32_bf16(ab, bb, c, 0, 0, 0);
}
__device__ __forceinline__ f32x4 mfma16(s16x8 a, s16x8 b, f32x4 c){
  return mfma_impl(a, b, c, 0);
}

__device__ __forceinline__ void gload_lds16(const u16* g, u16* l){
  __builtin_amdgcn_global_load_lds((const __attribute__((address_space(1))) void*)g,
                                   (__attribute__((address_space(3))) void*)l, 16, 0, 0);
}

// ---- K0: cast W_v, W_o to bf16 fragment layout; extract w_q column ----
// frag layout per W: [c 8][ks 8][nt 2][lane 64][j 8], element = W[ks*32+8*(l>>4)+j][c*32+nt*16+(l&15)]
__global__ void k0_prep(const float* __restrict__ Wqkv, const float* __restrict__ Wo,
                        u16* __restrict__ wvf, u16* __restrict__ wof, float* __restrict__ wqc){
  int t = blockIdx.x * 256 + threadIdx.x;
  if (t < 16384){
    int which = t >> 13;
    int slot  = t & 8191;
    int l  = slot & 63;
    int nt = (slot >> 6) & 1;
    int ks = (slot >> 7) & 7;
    int c  = (slot >> 10) & 7;
    int row = ks*32 + 8*(l>>4);
    int col = c*32 + nt*16 + (l&15);
    s16x8 o8;
    if (which == 0){
      for (int j=0;j<8;j++) o8[j] = (short)f2bf(Wqkv[(size_t)(row+j)*513 + 257 + col]);
      *(s16x8*)(wvf + (size_t)slot*8) = o8;
    } else {
      for (int j=0;j<8;j++) o8[j] = (short)f2bf(Wo[(size_t)(row+j)*256 + col]);
      *(s16x8*)(wof + (size_t)slot*8) = o8;
    }
  } else if (t < 16384 + 256){
    int d = t - 16384;
    wqc[d] = Wqkv[(size_t)d*513];    // W_qkv[:,0] contiguous copy
  }
}

// ---- K1: per 16-row tile: q = x.wq + b0 ; x -> bf16 A-frag layout ----
// x_frag: [bp 128][rt16 64][ks 8][lane 64][j 8], elem = x[rt16*16+(l&15)][ks*32+8*(l>>4)+j]
__global__ void k1_qfrag(const float* __restrict__ x, const float* __restrict__ wqc,
                         const float* __restrict__ bqkv, u16* __restrict__ xf, float* __restrict__ q){
  int bp = blockIdx.x >> 6, rt = blockIdx.x & 63;
  const float* xt = x + ((size_t)bp*NSEQ + rt*16) * EDIM;
  __shared__ float xl[16][260];     // +4 pad: breaks bank aliasing on strided row reads
  int tid = threadIdx.x;
  for (int i=0;i<4;i++){
    int idx = tid + i*256;
    float4 vv = ((const float4*)xt)[idx];
    int row = idx >> 6, c4 = idx & 63;
    *(float4*)&xl[row][c4*4] = vv;
  }
  __syncthreads();
  int l = tid & 63, w = tid >> 6;
  int lo = l & 15, hi = l >> 4;
  for (int kk=0;kk<2;kk++){
    int ks = w*2 + kk;
    int k0 = ks*32 + 8*hi;
    s16x8 o8;
    for (int j=0;j<8;j++) o8[j] = (short)f2bf(xl[lo][k0+j]);
    size_t fo = ((((size_t)bp*64 + rt)*8 + ks)*64 + l) * 8;
    *(s16x8*)(xf + fo) = o8;
  }
  // q rows: wave w handles rows 4w..4w+3, 64-lane dot over 256 cols
  int c = l*4;
  float4 wv4 = *(const float4*)(wqc + c);
  float b0 = bqkv[0];
  for (int r=0;r<4;r++){
    int row = w*4 + r;
    float4 xv = *(float4*)&xl[row][c];
    float p = xv.x*wv4.x + xv.y*wv4.y + xv.z*wv4.z + xv.w*wv4.w;
    for (int o=32;o;o>>=1) p += __shfl_down(p, o);
    if (l == 0) q[(size_t)bp*NSEQ + rt*16 + row] = p + b0;
  }
}

// ---- K234: per bp: softmax(q) -> t = s.x (from xf frags) -> cv = t.W_k + b_k ----
// 128 blocks x 512 threads (8 waves). Wave w owns ks=w for the t-reduction.
__global__ __launch_bounds__(512) void k234(
    const u16* __restrict__ xf, const float* __restrict__ q,
    const float* __restrict__ Wqkv, const float* __restrict__ bqkv,
    float* __restrict__ cv){
  int bp = blockIdx.x;
  int tid = threadIdx.x, l = tid & 63, w = tid >> 6;
  int lo = l & 15, hi = l >> 4;
  __shared__ float sm[1024];
  __shared__ float red[16];
  __shared__ float tl[256];
  __shared__ float cvp[2][256];

  // softmax over q[bp][:]
  float2 v = ((const float2*)(q + (size_t)bp*NSEQ))[tid];
  float m = fmaxf(v.x, v.y);
  for (int o=32;o;o>>=1) m = fmaxf(m, __shfl_xor(m, o));
  if (l == 0) red[w] = m;
  __syncthreads();
  m = red[0];
#pragma unroll
  for (int i=1;i<8;i++) m = fmaxf(m, red[i]);
  float e0 = expf(v.x - m), e1 = expf(v.y - m);
  float ss = e0 + e1;
  for (int o=32;o;o>>=1) ss += __shfl_xor(ss, o);
  if (l == 0) red[8 + w] = ss;
  __syncthreads();
  float tot = red[8];
#pragma unroll
  for (int i=1;i<8;i++) tot += red[8 + i];
  float inv = 1.0f / tot;
  sm[2*tid]   = e0 * inv;
  sm[2*tid+1] = e1 * inv;
  __syncthreads();

  // t accumulation: wave w handles ks=w, all 64 rt tiles
  float acc[8];
#pragma unroll
  for (int j=0;j<8;j++) acc[j] = 0.f;
  const u16* base = xf + (((size_t)bp*64)*8 + w)*512 + (size_t)l*8;
  for (int rt=0; rt<64; rt++){
    s16x8 d8 = *(const s16x8*)(base + (size_t)rt*4096);
    float sv = sm[rt*16 + lo];
#pragma unroll
    for (int j=0;j<8;j++) acc[j] += sv * bf2f((u16)d8[j]);
  }
#pragma unroll
  for (int j=0;j<8;j++)
    for (int mm=1;mm<16;mm<<=1) acc[j] += __shfl_xor(acc[j], mm);
  if (lo == 0){
#pragma unroll
    for (int j=0;j<8;j++) tl[w*32 + 8*hi + j] = acc[j];
  }
  __syncthreads();

  // cv = b_k + t . W_k   (threads split the d-range in halves)
  int e = tid & 255, half = tid >> 8;
  float a = 0.f;
  for (int d = half*128; d < half*128 + 128; d++)
    a += tl[d] * Wqkv[(size_t)d*513 + 1 + e];
  cvp[half][e] = a;
  __syncthreads();
  if (tid < 256)
    cv[(size_t)bp*EDIM + tid] = bqkv[1 + tid] + cvp[0][tid] + cvp[1][tid];
}

// ---- K5: out = (relu(x@Wv + bv) * cv) @ Wo + bo ----
// 4 waves x 32 rows (2 rowsets) = 128 rows/block; 1024 blocks.
// Fused 16-chunk loop (8 Wv then 8 Wo), 3-buffer LDS ring, prefetch depth 2,
// raw s_barrier + counted vmcnt (stores never drained). launch_bounds(256,2)
// keeps af/hf fragment arrays (128 VGPRs) register-resident.
__global__ __launch_bounds__(256, 2) void k5_main(
    const u16* __restrict__ xf, const u16* __restrict__ wvf, const u16* __restrict__ wof,
    const float* __restrict__ bqkv, const float* __restrict__ bo,
    const float* __restrict__ cv, float* __restrict__ out){
  int bp = blockIdx.x >> 3, rt = blockIdx.x & 7;
  int tid = threadIdx.x, l = tid & 63, w = tid >> 6;
  int lo = l & 15, hi = l >> 4;
  __shared__ u16 WBUF[3][16][512];   // 3-buffer ring of 16 KB W chunks (32 cols, full K)
  __shared__ u16 HB[4][2][16][40];   // per-wave, per-rowset h transpose slices

  // A-frags for 2 rowsets (16-row tiles 2w, 2w+1 of this 128-row block)
  s16x8 af0[8], af1[8];
  {
    const u16* src0 = xf + ((((size_t)bp*64 + rt*8 + 2*w + 0)*8)*64 + l)*8;
    const u16* src1 = src0 + 4096;
#pragma unroll
    for (int ks=0;ks<8;ks++){
      af0[ks] = *(const s16x8*)(src0 + (size_t)ks*512);
      af1[ks] = *(const s16x8*)(src1 + (size_t)ks*512);
    }
  }
  const float* cvb = cv + (size_t)bp*EDIM;
  float* ob0 = out + ((size_t)bp*NSEQ + (rt*8 + 2*w + 0)*16) * EDIM;
  float* ob1 = ob0 + 16*EDIM;

  // stage W chunk (0..7 = Wv, 8..15 = Wo) into ring buffer
  auto stage = [&](int chunk, int buf){
    const u16* base = (chunk < 8) ? (wvf + (size_t)chunk*8192) : (wof + (size_t)(chunk-8)*8192);
    const u16* gsrc = base + (size_t)(w*4)*512 + l*8;
#pragma unroll
    for (int i=0;i<4;i++) gload_lds16(gsrc + i*512, &WBUF[buf][w*4 + i][0]);
  };

  // prologue: stage chunks 0,1
  stage(0, 0);
  stage(1, 1);
  WAITVM(4);                       // chunk 0 staged (chunk 1's 4 loads may remain)
  __builtin_amdgcn_s_barrier();
  __builtin_amdgcn_sched_barrier(0);

  s16x8 hf0[8], hf1[8];

#pragma unroll
  for (int c=0;c<16;c++){
    const int buf = c % 3;
    f32x4 acc00 = {0.f,0.f,0.f,0.f}, acc01 = acc00, acc10 = acc00, acc11 = acc00;
    auto do_mfma = [&](const s16x8 (&A0)[8], const s16x8 (&A1)[8]){
      __builtin_amdgcn_s_setprio(1);
#pragma unroll
      for (int ks=0;ks<8;ks++){
        s16x8 b0 = *(const s16x8*)&WBUF[buf][ks*2 + 0][l*8];
        s16x8 b1 = *(const s16x8*)&WBUF[buf][ks*2 + 1][l*8];
        acc00 = mfma16(A0[ks], b0, acc00);
        acc10 = mfma16(A1[ks], b0, acc10);
        acc01 = mfma16(A0[ks], b1, acc01);
        acc11 = mfma16(A1[ks], b1, acc11);
      }
      __builtin_amdgcn_s_setprio(0);
    };
    if (c < 8) do_mfma(af0, af1); else do_mfma(hf0, hf1);

    if (c < 8){
      // epilogue A: h = relu(acc+bv)*cv -> HB scatter -> hf A-frags (wave-private LDS)
      int colA = c*32 + lo, colB = colA + 16;
      float bvA = bqkv[257 + colA], bvB = bqkv[257 + colB];
      float csA = cvb[colA],        csB = cvb[colB];
#pragma unroll
      for (int r=0;r<4;r++){
        float h00 = acc00[r] + bvA, h01 = acc01[r] + bvB;
        float h10 = acc10[r] + bvA, h11 = acc11[r] + bvB;
        HB[w][0][hi*4 + r][lo]      = f2bf(h00 > 0.f ? h00*csA : 0.f);
        HB[w][0][hi*4 + r][16 + lo] = f2bf(h01 > 0.f ? h01*csB : 0.f);
        HB[w][1][hi*4 + r][lo]      = f2bf(h10 > 0.f ? h10*csA : 0.f);
        HB[w][1][hi*4 + r][16 + lo] = f2bf(h11 > 0.f ? h11*csB : 0.f);
      }
      hf0[c] = *(const s16x8*)&HB[w][0][lo][8*hi];
      hf1[c] = *(const s16x8*)&HB[w][1][lo][8*hi];
    } else {
      // epilogue B: out stores (never drained by the counted waits below)
      int c2 = c - 8;
      int colA = c2*32 + lo, colB = colA + 16;
      float bbA = bo[colA], bbB = bo[colB];
#pragma unroll
      for (int r=0;r<4;r++){
        ob0[(size_t)(hi*4 + r)*EDIM + colA] = acc00[r] + bbA;
        ob0[(size_t)(hi*4 + r)*EDIM + colB] = acc01[r] + bbB;
        ob1[(size_t)(hi*4 + r)*EDIM + colA] = acc10[r] + bbA;
        ob1[(size_t)(hi*4 + r)*EDIM + colB] = acc11[r] + bbB;
      }
    }

    // stage chunk c+2 into the buffer freed at end of iter c-1
    if (c + 2 <= 15) stage(c + 2, (c + 2) % 3);

    // counted waits: ensure chunk c+1 staged; never drain this iter's stores.
    // A iters: younger ops = stage(c+2) only -> vmcnt(4).
    // B steady: queue = [prev stores 16][stage(c+1) 4][stores 16][stage(c+2) 4];
    //   vmcnt(20) retires prev stores + stage(c+1) exactly.
    // c=14: no stage -> vmcnt(16). c=15: done.
    if (c < 8)       WAITVM(4);
    else if (c < 14) WAITVM(20);
    else if (c == 14) WAITVM(16);
    if (c < 15){
      __builtin_amdgcn_s_barrier();
      __builtin_amdgcn_sched_barrier(0);
    }
  }
}

extern "C" void kernel_launch(void* const* d_in, const int* in_sizes, int n_in,
                              void* d_out, int out_size, void* d_ws, size_t ws_size,
                              hipStream_t stream){
  const float* x    = (const float*)d_in[0];
  const float* Wqkv = (const float*)d_in[1];
  const float* bqkv = (const float*)d_in[2];
  const float* Wo   = (const float*)d_in[3];
  const float* bo   = (const float*)d_in[4];
  float* out = (float*)d_out;
  char* ws = (char*)d_ws;
  u16*   xf  = (u16*)(ws);                       // 67108864 B
  u16*   wvf = (u16*)(ws + 67108864);            //   131072 B
  u16*   wof = (u16*)(ws + 67239936);            //   131072 B
  float* q   = (float*)(ws + 67371008);          //   524288 B
  float* cvv = (float*)(ws + 69468160);          //   131072 B
  float* wqc = (float*)(ws + 69599232);          //     1024 B

  hipLaunchKernelGGL(k0_prep,    dim3(65),   dim3(256), 0, stream, Wqkv, Wo, wvf, wof, wqc);
  hipLaunchKernelGGL(k1_qfrag,   dim3(8192), dim3(256), 0, stream, x, wqc, bqkv, xf, q);
  hipLaunchKernelGGL(k234,       dim3(128),  dim3(512), 0, stream, xf, q, Wqkv, bqkv, cvv);
  hipLaunchKernelGGL(k5_main,    dim3(1024), dim3(256), 0, stream, xf, wvf, wof, bqkv, bo, cvv, out);
}